// Round 2
// baseline (232.600 us; speedup 1.0000x reference)
//
#include <hip/hip_runtime.h>
#include <hip/hip_bf16.h>

#define NN 2048
#define FF 64
#define NH 8
#define BDIM 4
#define BH 32        // BDIM*NH
#define G 8          // rows per chunk
#define NC 256       // NN/G chunks per (b,head)
#define SCE 258      // NC+2 prefix entries per (b,head)

__device__ __forceinline__ float LDIN(const void* p, size_t i, int b16) {
    return b16 ? __bfloat162float(((const __hip_bfloat16*)p)[i]) : ((const float*)p)[i];
}

// ---------------- Kernel 0: detect input dtype (fp32 vs bf16) -----------------
__global__ void k_sniff(const void* __restrict__ h, int* __restrict__ flag) {
    int l = threadIdx.x;
    unsigned word = ((const unsigned*)h)[l];
    unsigned lowexp = (word >> 7) & 0xFFu;        // exponent of low half as bf16
    bool plaus = (lowexp >= 96u && lowexp <= 159u);
    unsigned long long m = __ballot(plaus);
    if (l == 0) flag[0] = (__popcll(m) >= 48) ? 1 : 0;
}

// ---------------- Kernel 1: h_prime = h@w (fp32), s/d via tanh dot-products ---
__global__ __launch_bounds__(512) void k_proj(
    const void* __restrict__ h, const void* __restrict__ w,
    const void* __restrict__ asrc, const void* __restrict__ adst,
    const int* __restrict__ flag,
    float* __restrict__ hp, float* __restrict__ sArr, float* __restrict__ dArr)
{
    const int b16 = flag[0];
    const int tid = threadIdx.x;
    const int hd = tid >> 6;        // head (wave id), 8 waves
    const int o  = tid & 63;        // output feature (lane)
    const int r0 = blockIdx.x * 8;  // row in [0, BDIM*NN)

    __shared__ float hrow[8][FF];
    hrow[tid >> 6][tid & 63] = LDIN(h, (size_t)(r0 + (tid >> 6)) * FF + (tid & 63), b16);
    __syncthreads();

    float acc[8];
#pragma unroll
    for (int r = 0; r < 8; ++r) acc[r] = 0.f;

    const size_t wbase = (size_t)hd * FF * FF + o;
#pragma unroll 8
    for (int f = 0; f < FF; ++f) {
        float wv = LDIN(w, wbase + (size_t)f * FF, b16);
#pragma unroll
        for (int r = 0; r < 8; ++r) acc[r] += hrow[r][f] * wv;
    }

    const float av = LDIN(asrc, hd * FF + o, b16);
    const float bv = LDIN(adst, hd * FF + o, b16);
    const int b  = r0 >> 11;
    const int bh = b * NH + hd;

#pragma unroll
    for (int r = 0; r < 8; ++r) {
        int i = (r0 + r) & (NN - 1);
        hp[((size_t)bh * NN + i) * FF + o] = acc[r];
        float t  = tanhf(acc[r]);
        float sv = t * av;
        float dv = t * bv;
#pragma unroll
        for (int off = 32; off >= 1; off >>= 1) {
            sv += __shfl_xor(sv, off, 64);
            dv += __shfl_xor(dv, off, 64);
        }
        if (o == 0) { sArr[bh * NN + i] = sv; dArr[bh * NN + i] = dv; }
    }
}

// ---------------- Kernel 2: per-(b,head) bitonic sort of d (ascending) --------
__global__ __launch_bounds__(1024) void k_sort(
    const float* __restrict__ dArr, float* __restrict__ sortedD, int* __restrict__ perm,
    float* __restrict__ eH, float* __restrict__ eL)
{
    __shared__ float key[NN];
    __shared__ int   sidx[NN];
    const unsigned tid = threadIdx.x;
    const int bh = blockIdx.x;

    for (int e = tid; e < NN; e += 1024) { key[e] = dArr[bh * NN + e]; sidx[e] = e; }
    __syncthreads();

    for (unsigned k = 2; k <= NN; k <<= 1) {
        for (unsigned j = k >> 1; j > 0; j >>= 1) {
            unsigned i = ((tid & ~(j - 1u)) << 1) | (tid & (j - 1u));
            unsigned p = i | j;
            bool up = ((i & k) == 0);
            float a = key[i], bb = key[p];
            if ((a > bb) == up) {
                key[i] = bb; key[p] = a;
                int ti = sidx[i]; sidx[i] = sidx[p]; sidx[p] = ti;
            }
            __syncthreads();
        }
    }
    for (int e = tid; e < NN; e += 1024) {
        float kv = key[e];
        sortedD[bh * NN + e] = kv;
        perm[bh * NN + e]    = sidx[e];
        eH[bh * NN + e]      = __expf(kv);
        eL[bh * NN + e]      = __expf(0.2f * kv);
    }
}

// ---------------- Kernel 3: per-chunk weighted sums (chunk = 8 rows) ----------
__global__ __launch_bounds__(256) void k_chunkA(
    const int* __restrict__ perm, const float* __restrict__ eH, const float* __restrict__ eL,
    const float* __restrict__ hp,
    float* __restrict__ cH, float* __restrict__ cL,
    float* __restrict__ cHs, float* __restrict__ cLs)
{
    const int bh  = blockIdx.x >> 4;
    const int grp = blockIdx.x & 15;
    const int wv  = threadIdx.x >> 6;
    const int o   = threadIdx.x & 63;

#pragma unroll
    for (int t = 0; t < 4; ++t) {
        const int c = grp * 16 + wv * 4 + t;     // chunk in [0, NC)
        float aH = 0.f, aL = 0.f, sH = 0.f, sL = 0.f;
#pragma unroll
        for (int mm = 0; mm < G; ++mm) {
            const int gm = bh * NN + c * G + mm;
            float e1 = eH[gm], e2 = eL[gm];
            int   j  = perm[gm];
            float v  = hp[((size_t)bh * NN + j) * FF + o];
            aH += e1 * v; aL += e2 * v; sH += e1; sL += e2;
        }
        cH[((size_t)bh * NC + c) * FF + o] = aH;
        cL[((size_t)bh * NC + c) * FF + o] = aL;
        if (o == 0) { cHs[bh * NC + c] = sH; cLs[bh * NC + c] = sL; }
    }
}

// ---------------- Kernel 4: chunk-granular suffix/prefix sums -----------------
__global__ __launch_bounds__(256) void k_scanB(
    const float* __restrict__ cH, const float* __restrict__ cL,
    const float* __restrict__ cHs, const float* __restrict__ cLs,
    float* __restrict__ SHc, float* __restrict__ SLc,
    float* __restrict__ shsc, float* __restrict__ slsc)
{
    const int bh = blockIdx.x;
    const int wv = threadIdx.x >> 6;
    const int o  = threadIdx.x & 63;

    if (wv == 0) {                       // SHc[c] = sum over chunks >= c (vector)
        float run = 0.f;
        SHc[((size_t)bh * SCE + NC) * FF + o] = 0.f;
        SHc[((size_t)bh * SCE + NC + 1) * FF + o] = 0.f;
        for (int c = NC - 1; c >= 0; --c) {
            run += cH[((size_t)bh * NC + c) * FF + o];
            SHc[((size_t)bh * SCE + c) * FF + o] = run;
        }
    } else if (wv == 1) {                // SLc[c] = sum over chunks < c (vector)
        float run = 0.f;
        for (int c = 0; c < NC; ++c) {
            SLc[((size_t)bh * SCE + c) * FF + o] = run;
            run += cL[((size_t)bh * NC + c) * FF + o];
        }
        SLc[((size_t)bh * SCE + NC) * FF + o] = run;
        SLc[((size_t)bh * SCE + NC + 1) * FF + o] = run;
    } else if (wv == 2 && o == 0) {      // scalar suffix
        float run = 0.f;
        shsc[bh * SCE + NC] = 0.f;
        shsc[bh * SCE + NC + 1] = 0.f;
        for (int c = NC - 1; c >= 0; --c) {
            run += cHs[bh * NC + c];
            shsc[bh * SCE + c] = run;
        }
    } else if (wv == 3 && o == 0) {      // scalar prefix (exclusive)
        float run = 0.f;
        for (int c = 0; c < NC; ++c) {
            slsc[bh * SCE + c] = run;
            run += cLs[bh * NC + c];
        }
        slsc[bh * SCE + NC] = run;
        slsc[bh * SCE + NC + 1] = run;
    }
}

// ---------------- Kernel 5: per-row search + partial chunk + combine ----------
__global__ __launch_bounds__(256) void k_out(
    const float* __restrict__ sArr, const float* __restrict__ sortedD,
    const int* __restrict__ perm, const float* __restrict__ eH, const float* __restrict__ eL,
    const float* __restrict__ hp,
    const float* __restrict__ SHc, const float* __restrict__ SLc,
    const float* __restrict__ shsc, const float* __restrict__ slsc,
    const void* __restrict__ bias, const int* __restrict__ flag, void* __restrict__ out)
{
    const int b16 = flag[0];
    const int bh = blockIdx.x >> 7;
    const int i0 = (blockIdx.x & 127) * 16;
    const int slot = threadIdx.x >> 6;
    const int o    = threadIdx.x & 63;

    __shared__ float sd[NN];
    for (int e = threadIdx.x; e < NN; e += 256) sd[e] = sortedD[bh * NN + e];
    __syncthreads();

    const float biasv = LDIN(bias, o, b16);

    for (int rr = 0; rr < 4; ++rr) {
        const int i = i0 + slot * 4 + rr;
        const float sv  = sArr[bh * NN + i];
        const float tau = -sv;
        int lo = 0, hi = NN;
        while (lo < hi) {               // first k with sd[k] >= tau
            int mid = (lo + hi) >> 1;
            if (sd[mid] < tau) lo = mid + 1; else hi = mid;
        }
        const int c0 = lo >> 3;
        const int m0 = c0 * G;
        const int mend = (m0 + G < NN) ? (m0 + G) : NN;

        float pH = 0.f, pL = 0.f, psH = 0.f, psL = 0.f;
        for (int m = m0; m < mend; ++m) {
            const int gm = bh * NN + m;
            float e1 = eH[gm], e2 = eL[gm];
            int   j  = perm[gm];
            float v  = hp[((size_t)bh * NN + j) * FF + o];
            if (m >= lo) { pH += e1 * v; psH += e1; }
            else         { pL += e2 * v; psL += e2; }
        }
        const size_t base = (size_t)bh * SCE;
        const float numH = SHc[(base + c0 + 1) * FF + o] + pH;
        const float numL = SLc[(base + c0) * FF + o] + pL;
        const float denH = shsc[base + c0 + 1] + psH;
        const float denL = slsc[base + c0] + psL;
        const float es  = __expf(sv);
        const float es2 = __expf(0.2f * sv);
        const float res = (es * numH + es2 * numL) / (es * denH + es2 * denL) + biasv;

        const size_t oi = ((size_t)bh * NN + i) * FF + o;
        if (b16) ((__hip_bfloat16*)out)[oi] = __float2bfloat16(res);
        else     ((float*)out)[oi] = res;
    }
}

extern "C" void kernel_launch(void* const* d_in, const int* in_sizes, int n_in,
                              void* d_out, int out_size, void* d_ws, size_t ws_size,
                              hipStream_t stream) {
    const void* h    = d_in[0];
    // d_in[1] = adj (bool) — unused by reference
    const void* w    = d_in[2];
    const void* asrc = d_in[3];
    const void* adst = d_in[4];
    const void* bias = d_in[5];

    float* ws = (float*)d_ws;
    int*   flag    = (int*)ws;                       // 4 ints
    float* hp      = ws + 4;                         // BH*NN*FF = 4,194,304
    float* sArr    = hp + (size_t)BH * NN * FF;      // 65,536
    float* dArr    = sArr + BH * NN;
    float* sortedD = dArr + BH * NN;
    int*   perm    = (int*)(sortedD + BH * NN);
    float* eH      = (float*)(perm + BH * NN);
    float* eL      = eH + BH * NN;
    float* cH      = eL + BH * NN;                   // BH*NC*FF = 524,288
    float* cL      = cH + (size_t)BH * NC * FF;
    float* cHs     = cL + (size_t)BH * NC * FF;      // BH*NC
    float* cLs     = cHs + BH * NC;
    float* SHc     = cLs + BH * NC;                  // BH*SCE*FF = 528,384
    float* SLc     = SHc + (size_t)BH * SCE * FF;
    float* shsc    = SLc + (size_t)BH * SCE * FF;    // BH*SCE
    float* slsc    = shsc + BH * SCE;

    k_sniff<<<1, 64, 0, stream>>>(h, flag);
    k_proj<<<(BDIM * NN) / 8, 512, 0, stream>>>(h, w, asrc, adst, flag, hp, sArr, dArr);
    k_sort<<<BH, 1024, 0, stream>>>(dArr, sortedD, perm, eH, eL);
    k_chunkA<<<BH * 16, 256, 0, stream>>>(perm, eH, eL, hp, cH, cL, cHs, cLs);
    k_scanB<<<BH, 256, 0, stream>>>(cH, cL, cHs, cLs, SHc, SLc, shsc, slsc);
    k_out<<<BH * 128, 256, 0, stream>>>(sArr, sortedD, perm, eH, eL, hp,
                                        SHc, SLc, shsc, slsc, bias, flag, d_out);
}